// Round 11
// baseline (6704.494 us; speedup 1.0000x reference)
//
#include <hip/hip_runtime.h>
#include <math.h>

#define NQ 9
#define S 16
#define H 128
#define BB 16
#define D 512
#define DD (D*D)
#define MAGIC 0x13579BDFu

typedef float vfloat4 __attribute__((ext_vector_type(4)));

__device__ __forceinline__ float sigf(float x){ return 1.f/(1.f + __expf(-x)); }
__device__ __forceinline__ float tanhfast(float x){
  float e = __expf(2.f*x);
  return 1.f - 2.f/(e + 1.f);
}
#define RCP(x)  __builtin_amdgcn_rcpf(x)
#define RSQ(x)  __builtin_amdgcn_rsqf(x)

#define DPP_ADD(x, ctrl, rmask) \
  x += __int_as_float(__builtin_amdgcn_update_dpp(0, __float_as_int(x), ctrl, rmask, 0xf, false))

__device__ __forceinline__ float wave_red_sum(float x) {
  DPP_ADD(x, 0x111, 0xf);   // row_shr:1
  DPP_ADD(x, 0x112, 0xf);   // row_shr:2
  DPP_ADD(x, 0x114, 0xf);   // row_shr:4
  DPP_ADD(x, 0x118, 0xf);   // row_shr:8
  DPP_ADD(x, 0x142, 0xa);   // row_bcast:15 -> rows 1,3
  DPP_ADD(x, 0x143, 0xc);   // row_bcast:31 -> rows 2,3
  return __int_as_float(__builtin_amdgcn_readlane(__float_as_int(x), 63));
}
#define RL(v, l) __int_as_float(__builtin_amdgcn_readlane(__float_as_int(v), (l)))
// row_ror:N: source lane = (i - N) mod 16. To read lane (i + half) use 16-half.
#define DPP_ROR(x, n) \
  __int_as_float(__builtin_amdgcn_update_dpp(0, __float_as_int(x), 0x120 + (n), 0xf, 0xf, false))

__device__ __forceinline__ void herm_entry(float4 m, int rb, int cb, float& er, float& ei) {
  if (rb == 0) { if (cb == 0) { er = m.x; ei = 0.f; } else { er = m.y; ei = m.z; } }
  else         { if (cb == 0) { er = m.y; ei = -m.z; } else { er = m.w; ei = 0.f; } }
}

__device__ __forceinline__ void nt_store4(float* p, float x, float y, float z, float w) {
  vfloat4 v; v.x = x; v.y = y; v.z = z; v.w = w;
  __builtin_nontemporal_store(v, (vfloat4*)p);
}

// ---------------------------------------------------------------------------
// Fused producer/consumer kernel, 272 blocks x 512 threads.
//   Blocks 0..15   : seq recurrence (one per batch). After emitting the 9
//                    Hermitian 2x2 mats for (b,t), release-store flag[b][t].
//   Blocks 16..271 : kron consumers. Each handles 4 (rTp,rg) units of one
//                    batch, accumulating per-t contributions as flags arrive
//                    (double-buffered LDS staging, 1 barrier/t).
// Residency safety: __launch_bounds__(512,4) caps VGPR<=128 -> 2 blocks/CU
// guaranteed -> capacity 512 blocks >= 272 grid (no spin deadlock).
// Flags live in d_ws, re-poisoned to 0xAAAAAAAA (!= MAGIC) before every
// timed launch.
// ---------------------------------------------------------------------------
__global__ __launch_bounds__(512, 4)
void fused_kernel(const float* __restrict__ snapshot,
                  const float* __restrict__ bcv,
                  const float* __restrict__ rho,
                  const float* __restrict__ h0,
                  const float* __restrict__ c0,
                  const float* __restrict__ W_ih,
                  const float* __restrict__ W_hh,
                  const float* __restrict__ b_ih,
                  const float* __restrict__ b_hh,
                  const float* __restrict__ Wp,
                  const float* __restrict__ bp,
                  float4* mats,              // ws: [BB][S][NQ]
                  unsigned int* flags,       // ws: [BB][S]
                  float* __restrict__ out,
                  float* __restrict__ last_bv)
{
  const int tid  = threadIdx.x;
  const int lane = tid & 63;

  __shared__ __align__(16) float xh[36];      // x: snap(9) + amps(27)
  __shared__ float gbuf[512];
  __shared__ float prj[27];
  __shared__ __align__(16) float2 stg[2][160];  // consumer staging (dbuf)

  if (blockIdx.x < BB) {
    // =================== PRODUCER: seq recurrence ===================
    const int b = blockIdx.x;
    const int w = tid >> 6;

    float4 wih[9], whh[32];
    {
      const float4* wi = (const float4*)(W_ih + tid*36);
      #pragma unroll
      for (int k = 0; k < 9; ++k) wih[k] = wi[k];
      const float4* wh = (const float4*)(W_hh + tid*H);
      #pragma unroll
      for (int k = 0; k < 32; ++k) whh[k] = wh[k];
    }
    const float bias = b_ih[tid] + b_hh[tid];
    float2 wpv[4]; float bpv[4];
    #pragma unroll
    for (int i = 0; i < 4; ++i) {
      int u = w + 8*i;
      if (u < 27) { wpv[i] = *(const float2*)(Wp + u*H + 2*lane); bpv[i] = bp[u]; }
      else        { wpv[i] = make_float2(0.f, 0.f); bpv[i] = 0.f; }
    }

    float cc0 = c0[b*H + 2*lane], cc1 = c0[b*H + 2*lane + 1];
    float h0v = h0[b*H + 2*lane], h1v = h0[b*H + 2*lane + 1];

    // pristine psi0 in wave-0 registers: flat = j*64 + lane
    float pr0[8], pi0[8], norm0 = 0.f;
    if (w == 0) {
      #pragma unroll
      for (int j = 0; j < 8; ++j) {
        pr0[j] = rho[b*1024 + j*64 + lane];
        pi0[j] = rho[b*1024 + 512 + j*64 + lane];
      }
      float ls = 0.f;
      #pragma unroll
      for (int j = 0; j < 8; ++j) ls += pr0[j]*pr0[j] + pi0[j]*pi0[j];
      norm0 = wave_red_sum(ls);
    }

    if (tid < NQ)  xh[tid]      = snapshot[b*NQ + tid];
    if (tid < 27)  xh[NQ + tid] = bcv[b*27 + tid];
    if (tid < NQ) {
      float s  = snapshot[b*NQ + tid];
      float v0 = bcv[b*27 + tid*3];
      float v1 = bcv[b*27 + tid*3 + 1];
      float v2 = bcv[b*27 + tid*3 + 2];
      mats[(b*S + 0)*NQ + tid] = make_float4(
          0.5f*(1.f + 3.f*s*v2), 1.5f*s*v0, -1.5f*s*v1, 0.5f*(1.f - 3.f*s*v2));
    }
    if (tid == 0)
      __hip_atomic_store(&flags[b*S + 0], MAGIC, __ATOMIC_RELEASE,
                         __HIP_MEMORY_SCOPE_AGENT);

    // pre-loop ghh from h0 registers (4 independent FMA chains)
    float ghh;
    {
      float g0 = bias, g1 = 0.f, g2 = 0.f, g3 = 0.f;
      #pragma unroll
      for (int j = 0; j < 32; ++j) {
        float4 wv = whh[j];
        g0 += wv.x*RL(h0v, 2*j);     g1 += wv.y*RL(h1v, 2*j);
        g2 += wv.z*RL(h0v, 2*j + 1); g3 += wv.w*RL(h1v, 2*j + 1);
      }
      ghh = (g0 + g1) + (g2 + g3);
    }
    __syncthreads();                                      // B0: xh ready

    for (int t = 1; t < S; ++t) {
      // gates = ghh + W_ih * x (9 LDS b128 broadcast reads)
      {
        const float4* x4 = (const float4*)xh;
        float g0 = ghh, g1 = 0.f, g2 = 0.f, g3 = 0.f;
        #pragma unroll
        for (int k = 0; k < 9; ++k) {
          float4 wv = wih[k], xv = x4[k];
          g0 += wv.x*xv.x; g1 += wv.y*xv.y; g2 += wv.z*xv.z; g3 += wv.w*xv.w;
        }
        gbuf[tid] = (g0 + g1) + (g2 + g3);
      }
      __syncthreads();                                    // B1: gbuf ready

      // cell update (every wave redundantly; h in registers)
      {
        float2 gI = *(const float2*)(gbuf + 2*lane);
        float2 gF = *(const float2*)(gbuf + 128 + 2*lane);
        float2 gG = *(const float2*)(gbuf + 256 + 2*lane);
        float2 gO = *(const float2*)(gbuf + 384 + 2*lane);
        cc0 = sigf(gF.x)*cc0 + sigf(gI.x)*tanhfast(gG.x);
        cc1 = sigf(gF.y)*cc1 + sigf(gI.y)*tanhfast(gG.y);
        h0v = sigf(gO.x)*tanhfast(cc0);
        h1v = sigf(gO.y)*tanhfast(cc1);
      }
      // projection logits: unit u = w + 8i
      #pragma unroll
      for (int i = 0; i < 4; ++i) {
        float p = wave_red_sum(wpv[i].x*h0v + wpv[i].y*h1v);
        int u = w + 8*i;
        if (u < 27 && lane == 0) prj[u] = p + bpv[i];
      }
      __syncthreads();                                    // B2: prj ready

      // wave 0: softmax -> amps; deferred-norm collapse; emit + flag
      if (w == 0) {
        float a1 = 0.f, a2 = 0.f, a3 = 0.f;
        float k0v = 0.f, k1rv = 0.f, k1iv = 0.f;
        if (lane < NQ) {
          float l0 = prj[lane*3], l1 = prj[lane*3+1], l2 = prj[lane*3+2];
          float mx = fmaxf(l0, fmaxf(l1, l2));
          float e0 = __expf(l0 - mx), e1 = __expf(l1 - mx), e2 = __expf(l2 - mx);
          float inv = RCP(e0 + e1 + e2);
          a1 = sqrtf(e0*inv); a2 = sqrtf(e1*inv); a3 = sqrtf(e2*inv);
          float an = sqrtf(a1*a1 + a2*a2 + a3*a3);
          float t3 = a3 + an;
          float n1 = RSQ(2.f*an*t3);
          k0v = n1*t3; k1rv = n1*a1; k1iv = -n1*a2;  // conj(p+)
        }
        float part[9];

        float r4[4], i4[4];
        {
          const float K0 = RL(k0v,0), K1r = RL(k1rv,0), K1i = RL(k1iv,0);
          float lp = 0.f;
          #pragma unroll
          for (int j = 0; j < 4; ++j) {
            r4[j] = K0*pr0[j] + K1r*pr0[j+4] - K1i*pi0[j+4];
            i4[j] = K0*pi0[j] + K1r*pi0[j+4] + K1i*pr0[j+4];
            lp += r4[j]*r4[j] + i4[j]*i4[j];
          }
          part[0] = lp;
        }
        float r2[2], i2[2];
        {
          const float K0 = RL(k0v,1), K1r = RL(k1rv,1), K1i = RL(k1iv,1);
          float lp = 0.f;
          #pragma unroll
          for (int j = 0; j < 2; ++j) {
            r2[j] = K0*r4[j] + K1r*r4[j+2] - K1i*i4[j+2];
            i2[j] = K0*i4[j] + K1r*i4[j+2] + K1i*r4[j+2];
            lp += r2[j]*r2[j] + i2[j]*i2[j];
          }
          part[1] = lp;
        }
        float wr, wi_;
        {
          const float K0 = RL(k0v,2), K1r = RL(k1rv,2), K1i = RL(k1iv,2);
          wr  = K0*r2[0] + K1r*r2[1] - K1i*i2[1];
          wi_ = K0*i2[0] + K1r*i2[1] + K1i*r2[1];
          part[2] = wr*wr + wi_*wi_;
        }
        #pragma unroll
        for (int q = 3; q < 5; ++q) {
          const int half = 32 >> (q - 3);
          const float K0 = RL(k0v,q), K1r = RL(k1rv,q), K1i = RL(k1iv,q);
          float pr = __shfl(wr,  lane + half, 64);
          float pi = __shfl(wi_, lane + half, 64);
          float nr = K0*wr  + K1r*pr - K1i*pi;
          float ni = K0*wi_ + K1r*pi + K1i*pr;
          wr = nr; wi_ = ni;
          part[q] = (lane < half) ? (nr*nr + ni*ni) : 0.f;
        }
        #pragma unroll
        for (int q = 5; q < NQ; ++q) {
          const int half = 32 >> (q - 3);
          const float K0 = RL(k0v,q), K1r = RL(k1rv,q), K1i = RL(k1iv,q);
          float pr, pi;
          if      (q == 5) { pr = DPP_ROR(wr, 8);  pi = DPP_ROR(wi_, 8);  }
          else if (q == 6) { pr = DPP_ROR(wr, 12); pi = DPP_ROR(wi_, 12); }
          else if (q == 7) { pr = DPP_ROR(wr, 14); pi = DPP_ROR(wi_, 14); }
          else             { pr = DPP_ROR(wr, 15); pi = DPP_ROR(wi_, 15); }
          float nr = K0*wr  + K1r*pr - K1i*pi;
          float ni = K0*wi_ + K1r*pi + K1i*pr;
          wr = nr; wi_ = ni;
          part[q] = (lane < half) ? (nr*nr + ni*ni) : 0.f;
        }
        float L[9];
        #pragma unroll
        for (int q = 0; q < NQ; ++q) L[q] = wave_red_sum(part[q]);
        float sv = 2.f*L[0] - norm0;
        #pragma unroll
        for (int q = 1; q < NQ; ++q) {
          float r = 2.f*L[q]*RCP(L[q-1]) - 1.f;
          sv = (lane == q) ? r : sv;
        }
        if (lane < NQ) {
          xh[lane] = sv;
          xh[9 + lane*3]     = a1;
          xh[9 + lane*3 + 1] = a2;
          xh[9 + lane*3 + 2] = a3;
          mats[(b*S + t)*NQ + lane] = make_float4(
              0.5f*(1.f + 3.f*sv*a3), 1.5f*sv*a1,
              -1.5f*sv*a2,            0.5f*(1.f - 3.f*sv*a3));
        }
        if (lane == 0)
          __hip_atomic_store(&flags[b*S + t], MAGIC, __ATOMIC_RELEASE,
                             __HIP_MEMORY_SCOPE_AGENT);
      }

      // ghh for next step (waves 1-7 overlap wave 0's collapse)
      if (t < S - 1) {
        float g0 = bias, g1 = 0.f, g2 = 0.f, g3 = 0.f;
        #pragma unroll
        for (int j = 0; j < 32; ++j) {
          float4 wv = whh[j];
          g0 += wv.x*RL(h0v, 2*j);     g1 += wv.y*RL(h1v, 2*j);
          g2 += wv.z*RL(h0v, 2*j + 1); g3 += wv.w*RL(h1v, 2*j + 1);
        }
        ghh = (g0 + g1) + (g2 + g3);
      }
      __syncthreads();                                    // B3: xh ready
    }

    if (tid < 27) last_bv[b*27 + tid] = xh[9 + tid];

  } else {
    // =================== CONSUMER: incremental kron ===================
    const int c   = blockIdx.x - BB;      // 0..255
    const int b   = c >> 4;               // batch
    const int sub = c & 15;               // units bm = sub*4 .. sub*4+3

    const int rb = tid >> 7;              // rB row within unit (0..3)
    const int c0 = (tid & 127) << 2;      // 4 consecutive cols
    const int cT = c0 >> 5, cB = c0 & 31;
    const float invS = 1.f/16.f;

    #pragma unroll
    for (int u = 0; u < 4; ++u) {
      const int bm  = sub*4 + u;
      const int rTp = bm >> 3;
      const int rg  = bm & 7;
      float4 a0r = make_float4(0,0,0,0), a0i = make_float4(0,0,0,0);
      float4 a1r = make_float4(0,0,0,0), a1i = make_float4(0,0,0,0);

      for (int t = 0; t < S; ++t) {
        // wait for mats[b][t] (acquire, agent scope; s_sleep backoff)
        while (__hip_atomic_load(&flags[b*S + t], __ATOMIC_ACQUIRE,
                                 __HIP_MEMORY_SCOPE_AGENT) != MAGIC) {
          __builtin_amdgcn_s_sleep(2);
        }
        const int buf = t & 1;
        // stage this t's factors: entries 0..31 top[rTi][cT], 32..159 bot[r][cB]
        if (tid < 160) {
          const float4* mrow = mats + (b*S + t)*NQ;
          float re = 1.f, im = 0.f;
          if (tid < 32) {
            int rTi = tid >> 4, cTl = tid & 15;
            int rT = rTp*2 + rTi;
            #pragma unroll
            for (int q = 0; q < 4; ++q) {
              int rbit = (rT >> (3 - q)) & 1, cbit = (cTl >> (3 - q)) & 1;
              float er, ei; herm_entry(mrow[q], rbit, cbit, er, ei);
              float nr = re*er - im*ei; im = re*ei + im*er; re = nr;
            }
          } else {
            int e = tid - 32;
            int r_ = e >> 5, cBl = e & 31;
            int rB = rg*4 + r_;
            #pragma unroll
            for (int q = 0; q < 5; ++q) {
              int rbit = (rB >> (4 - q)) & 1, cbit = (cBl >> (4 - q)) & 1;
              float er, ei; herm_entry(mrow[4 + q], rbit, cbit, er, ei);
              float nr = re*er - im*ei; im = re*ei + im*er; re = nr;
            }
          }
          stg[buf][tid] = make_float2(re, im);
        }
        __syncthreads();                 // stage(t) done (dbuf: no 2nd barrier)

        float2 tA = stg[buf][cT];
        float2 tB = stg[buf][16 + cT];
        const float2* bp2 = &stg[buf][32 + rb*32];
        float4 b01 = *(const float4*)&bp2[cB];
        float4 b23 = *(const float4*)&bp2[cB + 2];
        a0r.x += tA.x*b01.x - tA.y*b01.y;  a0i.x += tA.x*b01.y + tA.y*b01.x;
        a0r.y += tA.x*b01.z - tA.y*b01.w;  a0i.y += tA.x*b01.w + tA.y*b01.z;
        a0r.z += tA.x*b23.x - tA.y*b23.y;  a0i.z += tA.x*b23.y + tA.y*b23.x;
        a0r.w += tA.x*b23.z - tA.y*b23.w;  a0i.w += tA.x*b23.w + tA.y*b23.z;
        a1r.x += tB.x*b01.x - tB.y*b01.y;  a1i.x += tB.x*b01.y + tB.y*b01.x;
        a1r.y += tB.x*b01.z - tB.y*b01.w;  a1i.y += tB.x*b01.w + tB.y*b01.z;
        a1r.z += tB.x*b23.x - tB.y*b23.y;  a1i.z += tB.x*b23.y + tB.y*b23.x;
        a1r.w += tB.x*b23.z - tB.y*b23.w;  a1i.w += tB.x*b23.w + tB.y*b23.z;
      }

      const int rowA = (rTp*2)*32 + rg*4 + rb;
      const int rowB = rowA + 32;
      size_t baseA = ((size_t)b*2)*DD + (size_t)rowA*D + c0;
      size_t baseB = ((size_t)b*2)*DD + (size_t)rowB*D + c0;
      nt_store4(out + baseA,      a0r.x*invS, a0r.y*invS, a0r.z*invS, a0r.w*invS);
      nt_store4(out + baseA + DD, a0i.x*invS, a0i.y*invS, a0i.z*invS, a0i.w*invS);
      nt_store4(out + baseB,      a1r.x*invS, a1r.y*invS, a1r.z*invS, a1r.w*invS);
      nt_store4(out + baseB + DD, a1i.x*invS, a1i.y*invS, a1i.z*invS, a1i.w*invS);
    }
  }
}

extern "C" void kernel_launch(void* const* d_in, const int* in_sizes, int n_in,
                              void* d_out, int out_size, void* d_ws, size_t ws_size,
                              hipStream_t stream) {
  const float* snapshot = (const float*)d_in[0];
  const float* bcv      = (const float*)d_in[1];
  const float* rho      = (const float*)d_in[2];
  const float* h0       = (const float*)d_in[3];
  const float* c0       = (const float*)d_in[4];
  const float* W_ih     = (const float*)d_in[5];
  const float* W_hh     = (const float*)d_in[6];
  const float* b_ih     = (const float*)d_in[7];
  const float* b_hh     = (const float*)d_in[8];
  const float* Wp       = (const float*)d_in[9];
  const float* bp       = (const float*)d_in[10];

  float*        out     = (float*)d_out;
  float4*       mats    = (float4*)d_ws;                         // 36864 B
  unsigned int* flags   = (unsigned int*)((char*)d_ws + 36864);  // 256 x u32
  float*        last_bv = out + (size_t)BB*2*DD;                 // chunk 1

  fused_kernel<<<BB + 256, 512, 0, stream>>>(snapshot, bcv, rho, h0, c0,
                                             W_ih, W_hh, b_ih, b_hh, Wp, bp,
                                             mats, flags, out, last_bv);
}